// Round 1
// baseline (929.671 us; speedup 1.0000x reference)
//
#include <hip/hip_runtime.h>
#include <cstdio>
#include <cstdint>

// ---------------------------------------------------------------------------
// WindowAttention (swin-style) pipeline, bf16 MFMA:
//   cvt(x,wq,wp) -> GEMM1 qkv (+bias, Q*scale, scatter per-head) ->
//   attn per (window,head) -> GEMM2 proj (+bias) -> fp32 out
// Shapes: B=4096 N=49 C=384 H=12 HD=32 NW=64; M = 200704, K = 384.
// ---------------------------------------------------------------------------

typedef __attribute__((ext_vector_type(8))) short bfrag8;  // 8 bf16 (4 VGPR)
typedef __attribute__((ext_vector_type(4))) float facc4;   // MFMA accumulator

#define SCALE_Q 0.17677669529663687f

__device__ __forceinline__ unsigned short f2bf(float f) {  // fp32->bf16 RNE
  unsigned int x = __float_as_uint(f);
  x += 0x7fffu + ((x >> 16) & 1u);
  return (unsigned short)(x >> 16);
}

__device__ __forceinline__ void gload_lds16(const void* g, void* l) {
  __builtin_amdgcn_global_load_lds(
      (const __attribute__((address_space(1))) unsigned int*)g,
      (__attribute__((address_space(3))) unsigned int*)l,
      16, 0, 0);
}

// ---- fp32 -> bf16, 4 elems/thread (counts are exact multiples of 1024) ----
__global__ void __launch_bounds__(256) cvt_bf16_kernel(const float* __restrict__ src,
                                                       unsigned short* __restrict__ dst) {
  size_t i = ((size_t)blockIdx.x * 256u + threadIdx.x) * 4u;
  const float4 v = *(const float4*)(src + i);
  ushort4 o;
  o.x = f2bf(v.x); o.y = f2bf(v.y); o.z = f2bf(v.z); o.w = f2bf(v.w);
  *(ushort4*)(dst + i) = o;
}

// ---------------------------------------------------------------------------
// GEMM C = A * B^T (+bias). A: [M x 384] bf16 row-major, B: [N x 384] bf16
// row-major (weights, rows = output features). 128x128 tile, BK=64, 4 waves
// (2x2, 64x64 each), mfma_f32_16x16x32_bf16.
// MODE 0: qkv epilogue (bias, Q*=scale, scatter bf16 to (b,h,n,d))
// MODE 1: proj epilogue (bias, fp32 row-major out)
// LDS tiles [128][64] bf16, XOR-swizzled chunks: logical (row, cc) lives at
// byte row*128 + (cc ^ (row&7))*16. Staged with global_load_lds (linear LDS
// dest, pre-swizzled global source).
// ---------------------------------------------------------------------------
template <int NBLK, int MODE, int SWZ>
__global__ void __launch_bounds__(256) gemm_bt(
    const unsigned short* __restrict__ A, const unsigned short* __restrict__ B,
    const float* __restrict__ bias,
    unsigned short* __restrict__ q_out, unsigned short* __restrict__ k_out,
    unsigned short* __restrict__ v_out, float* __restrict__ f_out) {
  __shared__ unsigned short As[128 * 64];
  __shared__ unsigned short Bs[128 * 64];

  int bid = blockIdx.x;
  bid = (bid & 7) * SWZ + (bid >> 3);  // XCD-contiguous logical tiles
  const int bm = bid / NBLK, bn = bid % NBLK;
  const int tid = threadIdx.x;
  const int lane = tid & 63, wid = tid >> 6;
  const int wr = wid >> 1, wc = wid & 1;
  const int l15 = lane & 15, l4 = lane >> 4;

  const facc4 fz = {0.f, 0.f, 0.f, 0.f};
  facc4 acc[4][4];
#pragma unroll
  for (int i = 0; i < 4; ++i)
#pragma unroll
    for (int j = 0; j < 4; ++j) acc[i][j] = fz;

  const size_t a_row0 = (size_t)bm * 128;
  const size_t b_row0 = (size_t)bn * 128;

  for (int kt = 0; kt < 384; kt += 64) {
    // stage A and B: 1024 chunks of 16B each, 4 issues/thread/operand
#pragma unroll
    for (int i = 0; i < 4; ++i) {
      const int c = tid + (i << 8);          // chunk index 0..1023
      const int row = c >> 3, cc = c & 7;
      const int scc = cc ^ (row & 7);        // pre-swizzled source chunk
      const unsigned short* ga = A + (a_row0 + row) * 384 + kt + scc * 8;
      const unsigned short* gb = B + (b_row0 + row) * 384 + kt + scc * 8;
      char* ldsa = (char*)As + (((wid << 6) + (i << 8)) << 4);  // wave-uniform
      char* ldsb = (char*)Bs + (((wid << 6) + (i << 8)) << 4);
      gload_lds16(ga, ldsa);
      gload_lds16(gb, ldsb);
    }
    __syncthreads();
#pragma unroll
    for (int kk = 0; kk < 2; ++kk) {
      bfrag8 af[4], bf[4];
#pragma unroll
      for (int mi = 0; mi < 4; ++mi) {
        const int row = wr * 64 + mi * 16 + l15;
        const int ch = (kk * 4 + l4) ^ (row & 7);
        af[mi] = *(const bfrag8*)((const char*)As + row * 128 + ch * 16);
      }
#pragma unroll
      for (int ni = 0; ni < 4; ++ni) {
        const int row = wc * 64 + ni * 16 + l15;
        const int ch = (kk * 4 + l4) ^ (row & 7);
        bf[ni] = *(const bfrag8*)((const char*)Bs + row * 128 + ch * 16);
      }
#pragma unroll
      for (int mi = 0; mi < 4; ++mi)
#pragma unroll
        for (int ni = 0; ni < 4; ++ni)
          acc[mi][ni] = __builtin_amdgcn_mfma_f32_16x16x32_bf16(
              af[mi], bf[ni], acc[mi][ni], 0, 0, 0);
    }
    __syncthreads();
  }

  if (MODE == 0) {
    // qkv: col j -> t = j/384 (q/k/v), h = (j%384)/32, d = j%32
    unsigned short* op[4];
    float bv[4], sc[4];
#pragma unroll
    for (int ni = 0; ni < 4; ++ni) {
      const int j = bn * 128 + wc * 64 + ni * 16 + l15;
      const int t = j / 384;
      const int rj = j - t * 384;
      unsigned short* base = (t == 0) ? q_out : ((t == 1) ? k_out : v_out);
      op[ni] = base + (rj >> 5) * 1568 + (rj & 31);  // + h*49*32 + d
      bv[ni] = bias[j];
      sc[ni] = (t == 0) ? SCALE_Q : 1.0f;
    }
#pragma unroll
    for (int mi = 0; mi < 4; ++mi)
#pragma unroll
      for (int r = 0; r < 4; ++r) {
        const int m = bm * 128 + wr * 64 + mi * 16 + l4 * 4 + r;
        const unsigned int bq = (unsigned int)m / 49u;
        const unsigned int nn = (unsigned int)m - bq * 49u;
        const size_t ro = (size_t)bq * 18816u + (size_t)nn * 32u;  // b*12*1568 + n*32
#pragma unroll
        for (int ni = 0; ni < 4; ++ni)
          op[ni][ro] = f2bf((acc[mi][ni][r] + bv[ni]) * sc[ni]);
      }
  } else {
    float bv[4];
#pragma unroll
    for (int ni = 0; ni < 4; ++ni)
      bv[ni] = bias[bn * 128 + wc * 64 + ni * 16 + l15];
#pragma unroll
    for (int mi = 0; mi < 4; ++mi)
#pragma unroll
      for (int r = 0; r < 4; ++r) {
        const int m = bm * 128 + wr * 64 + mi * 16 + l4 * 4 + r;
        float* orow = f_out + (size_t)m * 384 + bn * 128 + wc * 64 + l15;
#pragma unroll
        for (int ni = 0; ni < 4; ++ni) orow[ni * 16] = acc[mi][ni][r] + bv[ni];
      }
  }
}

// ---------------------------------------------------------------------------
// Attention: one wave per (window b, head h). Q,K,V: [49x32] bf16 per head,
// padded to 64 rows (zeros). S = Q K^T (Q pre-scaled), + mask[b%64] (pads get
// -1e30), softmax (shfl_xor over 16-lane groups), P -> LDS bf16, O = P V,
// normalized by row sum at the end. Output scattered to (b, n, h, d) bf16.
// ---------------------------------------------------------------------------
__global__ void __launch_bounds__(64) attn_kernel(
    const unsigned short* __restrict__ Qg, const unsigned short* __restrict__ Kg,
    const unsigned short* __restrict__ Vg, const float* __restrict__ maskg,
    unsigned short* __restrict__ Og) {
  __shared__ unsigned short Qs[64 * 32];   // [n][d], chunk-swizzled
  __shared__ unsigned short Ks[64 * 32];   // [n][d], chunk-swizzled
  __shared__ unsigned short Vt[32 * 64];   // [d][n], byte-XOR swizzled
  __shared__ unsigned short Ps[64 * 64];   // [m][n], byte-XOR swizzled

  const int bid = blockIdx.x;
  const int b = bid / 12, h = bid - b * 12;
  const int lane = threadIdx.x;
  const int l15 = lane & 15, l4 = lane >> 4;

  const bfrag8 z8 = {0, 0, 0, 0, 0, 0, 0, 0};
  const facc4 fz = {0.f, 0.f, 0.f, 0.f};

  // zero-fill padded staging buffers (rows/cols 49..63)
#pragma unroll
  for (int i = 0; i < 4; ++i) {
    *(bfrag8*)((char*)Qs + (lane + i * 64) * 16) = z8;
    *(bfrag8*)((char*)Ks + (lane + i * 64) * 16) = z8;
    *(bfrag8*)((char*)Vt + (lane + i * 64) * 16) = z8;
  }

  const size_t hb = (size_t)(b * 12 + h) * 1568;  // 49*32 elems per head
  const unsigned short* qsrc = Qg + hb;
  const unsigned short* ksrc = Kg + hb;
  const unsigned short* vsrc = Vg + hb;
#pragma unroll
  for (int i = 0; i < 4; ++i) {
    const int c = lane + i * 64;  // 16B chunk; 196 real chunks (49*32*2B)
    if (c < 196) {
      const bfrag8 qv = *(const bfrag8*)(qsrc + c * 8);
      const bfrag8 kv = *(const bfrag8*)(ksrc + c * 8);
      const bfrag8 vv = *(const bfrag8*)(vsrc + c * 8);
      const int n = c >> 2, cc = c & 3;
      const int dsoff = n * 64 + ((cc ^ (n & 3)) << 4);
      *(bfrag8*)((char*)Qs + dsoff) = qv;
      *(bfrag8*)((char*)Ks + dsoff) = kv;
      const int d0 = cc * 8;  // transpose V into Vt[d][n]
#pragma unroll
      for (int jj = 0; jj < 8; ++jj) {
        const int d = d0 + jj;
        *(unsigned short*)((char*)Vt + (((d << 7) + (n << 1)) ^ ((d & 7) << 4))) =
            (unsigned short)vv[jj];
      }
    }
  }
  __syncthreads();

  // S = Q K^T  (16x16x32, 4x4 fragments)
  facc4 s[4][4];
  {
    bfrag8 af[4], bf[4];
#pragma unroll
    for (int mi = 0; mi < 4; ++mi) {
      const int row = mi * 16 + l15;
      af[mi] = *(const bfrag8*)((const char*)Qs + row * 64 + ((l4 ^ (row & 3)) << 4));
    }
#pragma unroll
    for (int ni = 0; ni < 4; ++ni) {
      const int row = ni * 16 + l15;
      bf[ni] = *(const bfrag8*)((const char*)Ks + row * 64 + ((l4 ^ (row & 3)) << 4));
    }
#pragma unroll
    for (int mi = 0; mi < 4; ++mi)
#pragma unroll
      for (int ni = 0; ni < 4; ++ni)
        s[mi][ni] = __builtin_amdgcn_mfma_f32_16x16x32_bf16(af[mi], bf[ni], fz, 0, 0, 0);
  }

  // mask + softmax. acc layout: n = ni*16 + l15, m = mi*16 + l4*4 + r
  const float* mp = maskg + (size_t)(b & 63) * 2401;
  float rinv[4][4];
#pragma unroll
  for (int mi = 0; mi < 4; ++mi)
#pragma unroll
    for (int r = 0; r < 4; ++r) {
      const int m = mi * 16 + l4 * 4 + r;
      float mx = -1e30f;
#pragma unroll
      for (int ni = 0; ni < 4; ++ni) {
        const int n = ni * 16 + l15;
        const float add = (m < 49 && n < 49) ? mp[m * 49 + n] : -1e30f;
        const float v = s[mi][ni][r] + add;
        s[mi][ni][r] = v;
        mx = fmaxf(mx, v);
      }
      mx = fmaxf(mx, __shfl_xor(mx, 1));
      mx = fmaxf(mx, __shfl_xor(mx, 2));
      mx = fmaxf(mx, __shfl_xor(mx, 4));
      mx = fmaxf(mx, __shfl_xor(mx, 8));
      float sum = 0.f;
#pragma unroll
      for (int ni = 0; ni < 4; ++ni) {
        const float p = __expf(s[mi][ni][r] - mx);
        s[mi][ni][r] = p;
        sum += p;
      }
      sum += __shfl_xor(sum, 1);
      sum += __shfl_xor(sum, 2);
      sum += __shfl_xor(sum, 4);
      sum += __shfl_xor(sum, 8);
      rinv[mi][r] = 1.0f / sum;
#pragma unroll
      for (int ni = 0; ni < 4; ++ni) {
        const int n = ni * 16 + l15;
        *(unsigned short*)((char*)Ps + (((m << 7) + (n << 1)) ^ ((m & 7) << 4))) =
            f2bf(s[mi][ni][r]);
      }
    }
  __syncthreads();

  // O = P V (unnormalized), then scale by 1/rowsum
  facc4 o[4][2];
#pragma unroll
  for (int mi = 0; mi < 4; ++mi)
#pragma unroll
    for (int di = 0; di < 2; ++di) o[mi][di] = fz;
#pragma unroll
  for (int kk = 0; kk < 2; ++kk) {
    bfrag8 pa[4], vb[2];
#pragma unroll
    for (int mi = 0; mi < 4; ++mi) {
      const int row = mi * 16 + l15;
      pa[mi] = *(const bfrag8*)((const char*)Ps +
                                (((row << 7) + kk * 64 + (l4 << 4)) ^ ((row & 7) << 4)));
    }
#pragma unroll
    for (int di = 0; di < 2; ++di) {
      const int row = di * 16 + l15;
      vb[di] = *(const bfrag8*)((const char*)Vt +
                                (((row << 7) + kk * 64 + (l4 << 4)) ^ ((row & 7) << 4)));
    }
#pragma unroll
    for (int mi = 0; mi < 4; ++mi)
#pragma unroll
      for (int di = 0; di < 2; ++di)
        o[mi][di] = __builtin_amdgcn_mfma_f32_16x16x32_bf16(pa[mi], vb[di], o[mi][di], 0, 0, 0);
  }

  unsigned short* op = Og + (size_t)b * 18816 + h * 32;  // (b, n, h, d)
#pragma unroll
  for (int mi = 0; mi < 4; ++mi)
#pragma unroll
    for (int r = 0; r < 4; ++r) {
      const int m = mi * 16 + l4 * 4 + r;
      if (m < 49) {
        const float rs = rinv[mi][r];
#pragma unroll
        for (int di = 0; di < 2; ++di)
          op[(size_t)m * 384 + di * 16 + l15] = f2bf(o[mi][di][r] * rs);
      }
    }
}

// ---------------------------------------------------------------------------
extern "C" void kernel_launch(void* const* d_in, const int* in_sizes, int n_in,
                              void* d_out, int out_size, void* d_ws, size_t ws_size,
                              hipStream_t stream) {
  const float* x      = (const float*)d_in[0];  // (4096, 49, 384)
  const float* mask   = (const float*)d_in[1];  // (64, 49, 49)
  const float* w_qkv  = (const float*)d_in[2];  // (1152, 384)
  const float* b_qkv  = (const float*)d_in[3];  // (1152,)
  const float* w_proj = (const float*)d_in[4];  // (384, 384)
  const float* b_proj = (const float*)d_in[5];  // (384,)
  float* out = (float*)d_out;

  // workspace layout (unsigned short elements)
  const size_t E = 77070336ull;  // 200704*384 == 49152*1568
  unsigned short* wsu  = (unsigned short*)d_ws;
  unsigned short* q_ws = wsu;
  unsigned short* k_ws = wsu + E;
  unsigned short* v_ws = wsu + 2 * E;
  unsigned short* o_ws = wsu + 3 * E;
  unsigned short* xbf  = wsu + 4 * E;
  unsigned short* wqb  = wsu + 5 * E;
  unsigned short* wpb  = wqb + 442368ull;
  const size_t need = (5 * E + 442368ull + 147456ull) * 2ull;
  if (ws_size < need) {
    fprintf(stderr, "[WindowAttention] ws too small: need=%zu have=%zu\n",
            (size_t)need, ws_size);
    return;
  }

  // fp32 -> bf16 conversions (element counts all multiples of 1024)
  cvt_bf16_kernel<<<75264, 256, 0, stream>>>(x, xbf);
  cvt_bf16_kernel<<<432, 256, 0, stream>>>(w_qkv, wqb);
  cvt_bf16_kernel<<<144, 256, 0, stream>>>(w_proj, wpb);

  // QKV projection: M=200704, N=1152, K=384 -> grid 1568*9 = 14112 (= 8*1764)
  gemm_bt<9, 0, 1764><<<14112, 256, 0, stream>>>(xbf, wqb, b_qkv,
                                                 q_ws, k_ws, v_ws, nullptr);

  // attention: one wave per (b, h)
  attn_kernel<<<49152, 64, 0, stream>>>(q_ws, k_ws, v_ws, mask, o_ws);

  // output projection: M=200704, N=384, K=384 -> grid 1568*3 = 4704 (= 8*588)
  gemm_bt<3, 1, 588><<<4704, 256, 0, stream>>>(o_ws, wpb, b_proj,
                                               nullptr, nullptr, nullptr, out);
}